// Round 7
// baseline (4118.601 us; speedup 1.0000x reference)
//
#include <hip/hip_runtime.h>

#define BB 128
#define TT 2048
#define DD 64
#define HH 128
#define OO 32
#define NB 16
#define SCALE 2.885390081777927f   // 2/ln2: folded into weights so tanh = 1-2*rcp(1+exp2(z))

typedef _Float16 f16x8 __attribute__((ext_vector_type(8)));
typedef __fp16   pk16x2 __attribute__((ext_vector_type(2)));
typedef float    f32x4 __attribute__((ext_vector_type(4)));

#define MFMA16(a,b,c) __builtin_amdgcn_mfma_f32_16x16x32_f16((a),(b),(c),0,0,0)

__device__ __forceinline__ f32x4 load4(const float* p){ return *(const f32x4*)p; }

// A-fragment for 16x16x32 (A[m=lane&15][k=(lane>>4)*8+j]), scaled on load.
__device__ __forceinline__ f16x8 afrag_s(const float* p, float s){
    float4 a = *(const float4*)p, b = *(const float4*)(p+4);
    f16x8 r;
    r[0]=(_Float16)(a.x*s); r[1]=(_Float16)(a.y*s); r[2]=(_Float16)(a.z*s); r[3]=(_Float16)(a.w*s);
    r[4]=(_Float16)(b.x*s); r[5]=(_Float16)(b.y*s); r[6]=(_Float16)(b.z*s); r[7]=(_Float16)(b.w*s);
    return r;
}

// tanh(u) with z = SCALE*u pre-scaled: e = 2^z = e^{2u}; tanh = 1 - 2/(1+e).
__device__ __forceinline__ float tanh_pre(float z){
#if __has_builtin(__builtin_amdgcn_exp2f)
    float e = __builtin_amdgcn_exp2f(z);
#else
    float e = exp2f(z);
#endif
    return __builtin_fmaf(-2.f, __builtin_amdgcn_rcpf(1.f + e), 1.f);
}

__device__ __forceinline__ unsigned pk2(float a, float b){
    union { pk16x2 h; unsigned u; } c;
    c.h = __builtin_amdgcn_cvt_pkrtz(a, b);
    return c.u;
}

// ---- FIFO flags: single-producer single-consumer, workgroup scope ----
__device__ __forceinline__ unsigned ld_flag(const unsigned* p){
    return __hip_atomic_load(p, __ATOMIC_ACQUIRE, __HIP_MEMORY_SCOPE_WORKGROUP);
}
__device__ __forceinline__ void st_flag(unsigned* p, unsigned v){
    __hip_atomic_store(p, v, __ATOMIC_RELEASE, __HIP_MEMORY_SCOPE_WORKGROUP);
}

// ---- swizzled state-slot helpers ----
// Row n = 64 dwords (128 halves). 4-dword chunks XOR-swizzled by s=(n>>1)&7:
// uniform over the 8 bank-groups for both C-layout b64 writes and B-frag b128
// reads -> conflict-free (64-lane optimum).
__device__ __forceinline__ void read_frags(const unsigned* slot, int n, int q, int swz,
                                           f16x8* f){
    #pragma unroll
    for (int kt = 0; kt < 4; ++kt){
        const int c4 = (kt*4 + q) ^ swz;
        f[kt] = *(const f16x8*)&slot[n*64 + c4*4];
    }
}
__device__ __forceinline__ void write_pack(unsigned* slot, int n, int q, int swz,
                                           const unsigned P[8][2]){
    #pragma unroll
    for (int mt = 0; mt < 8; ++mt){
        const int c4 = (mt*2 + (q>>1)) ^ swz;
        uint2 v; v.x = P[mt][0]; v.y = P[mt][1];
        *(uint2*)&slot[n*64 + c4*4 + (q&1)*2] = v;
    }
}
__device__ __forceinline__ void tanh_pack(const f32x4* z, unsigned P[8][2]){
    #pragma unroll
    for (int mt = 0; mt < 8; ++mt){
        float t0 = tanh_pre(z[mt][0]), t1 = tanh_pre(z[mt][1]);
        float t2 = tanh_pre(z[mt][2]), t3 = tanh_pre(z[mt][3]);
        P[mt][0] = pk2(t0, t1); P[mt][1] = pk2(t2, t3);
    }
}

// ---------------------------------------------------------------------------
// proj: xp0[bt][i] = SCALE * (W_ih0[i,:].x[bt,:] + b_ih0[i] + b_hh0[i]), fp16.
// ---------------------------------------------------------------------------
#define XSTR 72
extern "C" __global__ void __launch_bounds__(256)
proj_kernel(const float* __restrict__ x, const float* __restrict__ W_ih0,
            const float* __restrict__ b_ih0, const float* __restrict__ b_hh0,
            _Float16* __restrict__ xp0)
{
    const int tid = threadIdx.x;
    const int w = tid >> 6, lane = tid & 63;
    const int n = lane & 15, q = lane >> 4;
    const size_t row0 = (size_t)blockIdx.x * 64;

    __shared__ __align__(16) _Float16 XT[64][XSTR];

    #pragma unroll
    for (int it = 0; it < 4; ++it){
        float4 v = *(const float4*)(x + row0*DD + it*1024 + tid*4);
        int rr = it*16 + (tid >> 4), d0 = (tid & 15)*4;
        union { uint2 u; _Float16 h[4]; } c;
        c.h[0]=(_Float16)v.x; c.h[1]=(_Float16)v.y; c.h[2]=(_Float16)v.z; c.h[3]=(_Float16)v.w;
        *(uint2*)&XT[rr][d0] = c.u;
    }

    f16x8 A[8][2]; f32x4 bv[8];
    #pragma unroll
    for (int mt = 0; mt < 8; ++mt){
        #pragma unroll
        for (int kt = 0; kt < 2; ++kt)
            A[mt][kt] = afrag_s(W_ih0 + (mt*16 + n)*DD + kt*32 + q*8, SCALE);
        bv[mt] = (load4(b_ih0 + mt*16 + q*4) + load4(b_hh0 + mt*16 + q*4)) * SCALE;
    }
    __syncthreads();

    const _Float16* xr = &XT[w*16 + n][0];
    f16x8 B0 = *(const f16x8*)(xr + q*8);
    f16x8 B1 = *(const f16x8*)(xr + 32 + q*8);

    _Float16* orow = xp0 + (row0 + w*16 + n)*HH + q*4;
    #pragma unroll
    for (int mt = 0; mt < 8; ++mt){
        f32x4 acc = bv[mt];
        acc = MFMA16(A[mt][0], B0, acc);
        acc = MFMA16(A[mt][1], B1, acc);
        union { uint2 u; _Float16 h[4]; } s;
        #pragma unroll
        for (int r = 0; r < 4; ++r) s.h[r] = (_Float16)acc[r];
        *(uint2*)(orow + mt*16) = s.u;
    }
}

// ---------------------------------------------------------------------------
// fill: out[b][t][:] = b_fc for t >= lengths[b].
// ---------------------------------------------------------------------------
extern "C" __global__ void __launch_bounds__(256)
fill_kernel(const int* __restrict__ lengths, const float* __restrict__ b_fc,
            float* __restrict__ out)
{
    size_t idx = (size_t)blockIdx.x*256 + threadIdx.x;
    #pragma unroll
    for (int k = 0; k < 4; ++k, idx += (size_t)2048*256){
        int o4 = (int)(idx & 7);
        int t  = (int)((idx >> 3) & 2047);
        int b  = (int)(idx >> 14);
        if (t >= lengths[b])
            ((float4*)out)[idx] = *(const float4*)(b_fc + o4*4);
    }
}

// ---------------------------------------------------------------------------
// scan_pipe: 8 blocks x 256 thr. Block = 16 rows. Wave roles (no barriers):
//  w0 A : h1[t] = tanh(Whh0.h1[t-1] + xp[t])       (full M=128 in one wave)
//  w1 B1: u[t]  = Wih1.h1[t] + b1                   (non-recurrent)
//  w2 B2: h2[t] = tanh(u[t] + Whh1.h2[t-1])
//  w3 C : out[t] = Wfc.h2[t] + b_fc  (t < len)
// Recurrence state transform (C-layout -> B-frags) is a private swizzled LDS
// round-trip (in-order DS pipe, intra-wave => no sync). Handoffs: depth-4
// FIFOs + acquire/release flags; A free-runs up to 4 steps ahead.
// ---------------------------------------------------------------------------
extern "C" __global__ void __launch_bounds__(256, 1)
scan_pipe(const _Float16* __restrict__ xp0, const int* __restrict__ lengths,
          const float* __restrict__ W_hh0,
          const float* __restrict__ W_ih1, const float* __restrict__ W_hh1,
          const float* __restrict__ b_ih1, const float* __restrict__ b_hh1,
          const float* __restrict__ W_fc,  const float* __restrict__ b_fc,
          float* __restrict__ out)
{
    const int tid  = threadIdx.x;
    const int w    = tid >> 6, lane = tid & 63;
    const int n    = lane & 15, q = lane >> 4;
    const int swz  = (n >> 1) & 7;
    const int rbase = blockIdx.x * NB;

    __shared__ __align__(16) unsigned h1slot[4][NB*64];   // 4 x 4 KB
    __shared__ __align__(16) unsigned h2slot[4][NB*64];   // 4 x 4 KB
    __shared__ __align__(16) f32x4    uslot[4][64*8];     // 4 x 8 KB
    __shared__ unsigned flg[8]; // 0 h1_prod 1 h1_cons 2 u_prod 3 u_cons 4 h2_prod 5 h2_cons

    if (tid < 8) flg[tid] = 0u;

    const int lenn = lengths[rbase + n];
    int mx = lenn;
    #pragma unroll
    for (int s = 1; s < 16; s <<= 1){ int o = __shfl_xor(mx, s, 64); mx = max(mx, o); }
    const int maxlen = __builtin_amdgcn_readfirstlane(mx);

    __syncthreads();   // flags visible; the ONLY barrier in this kernel

    if (w == 0){
        // ---------------- wave A: layer-0 recurrence ----------------
        f16x8 A0[8][4];
        #pragma unroll
        for (int mt = 0; mt < 8; ++mt)
            #pragma unroll
            for (int kt = 0; kt < 4; ++kt)
                A0[mt][kt] = afrag_s(W_hh0 + (mt*16 + n)*HH + kt*32 + q*8, SCALE);

        const _Float16* xpb = xp0 + (size_t)(rbase + n)*TT*HH + q*4;
        uint2 xc[8], xn[8];
        #pragma unroll
        for (int mt = 0; mt < 8; ++mt) xc[mt] = *(const uint2*)(xpb + mt*16);
        #pragma unroll
        for (int mt = 0; mt < 8; ++mt)
            xn[mt] = (1 < maxlen) ? *(const uint2*)(xpb + HH + mt*16) : xc[mt];

        f16x8 bh1[4];
        #pragma unroll
        for (int kt = 0; kt < 4; ++kt) bh1[kt] = (f16x8)(_Float16)0;

        unsigned cons = 0;
        for (int t = 0; t < maxlen; ++t){
            if (t >= 4 && cons < (unsigned)(t-3)){
                do { cons = ld_flag(&flg[1]); } while (cons < (unsigned)(t-3));
            }
            f32x4 z[8];
            #pragma unroll
            for (int mt = 0; mt < 8; ++mt){
                union { uint2 u; _Float16 h[4]; } c; c.u = xc[mt];
                z[mt][0]=(float)c.h[0]; z[mt][1]=(float)c.h[1];
                z[mt][2]=(float)c.h[2]; z[mt][3]=(float)c.h[3];
            }
            if (t + 2 < maxlen){
                #pragma unroll
                for (int mt = 0; mt < 8; ++mt)
                    xc[mt] = *(const uint2*)(xpb + (size_t)(t+2)*HH + mt*16);
            }
            #pragma unroll
            for (int kt = 0; kt < 4; ++kt)
                #pragma unroll
                for (int mt = 0; mt < 8; ++mt)
                    z[mt] = MFMA16(A0[mt][kt], bh1[kt], z[mt]);

            unsigned P[8][2];
            tanh_pack(z, P);
            unsigned* slot = h1slot[t & 3];
            write_pack(slot, n, q, swz, P);
            read_frags(slot, n, q, swz, bh1);      // own next-step B-frags
            if (lane == 0) st_flag(&flg[0], (unsigned)(t+1));

            #pragma unroll
            for (int mt = 0; mt < 8; ++mt){ uint2 tmp = xc[mt]; xc[mt] = xn[mt]; xn[mt] = tmp; }
        }
    } else if (w == 1){
        // ---------------- wave B1: u = Wih1.h1 + b1 ----------------
        f16x8 Ai[8][4]; f32x4 b1v[8];
        #pragma unroll
        for (int mt = 0; mt < 8; ++mt){
            #pragma unroll
            for (int kt = 0; kt < 4; ++kt)
                Ai[mt][kt] = afrag_s(W_ih1 + (mt*16 + n)*HH + kt*32 + q*8, SCALE);
            b1v[mt] = (load4(b_ih1 + mt*16 + q*4) + load4(b_hh1 + mt*16 + q*4)) * SCALE;
        }
        unsigned prod = 0, cons = 0;
        const int l7 = lane & 7;
        for (int t = 0; t < maxlen; ++t){
            if (prod <= (unsigned)t){
                do { prod = ld_flag(&flg[0]); } while (prod <= (unsigned)t);
            }
            f16x8 bh1[4];
            read_frags(h1slot[t & 3], n, q, swz, bh1);
            if (t >= 4 && cons < (unsigned)(t-3)){
                do { cons = ld_flag(&flg[3]); } while (cons < (unsigned)(t-3));
            }
            f32x4 u[8];
            #pragma unroll
            for (int mt = 0; mt < 8; ++mt) u[mt] = b1v[mt];
            #pragma unroll
            for (int kt = 0; kt < 4; ++kt)
                #pragma unroll
                for (int mt = 0; mt < 8; ++mt)
                    u[mt] = MFMA16(Ai[mt][kt], bh1[kt], u[mt]);
            f32x4* us = uslot[t & 3];
            #pragma unroll
            for (int mt = 0; mt < 8; ++mt) us[lane*8 + (mt ^ l7)] = u[mt];
            if (lane == 0){ st_flag(&flg[1], (unsigned)(t+1)); st_flag(&flg[2], (unsigned)(t+1)); }
        }
    } else if (w == 2){
        // ---------------- wave B2: layer-1 recurrence ----------------
        f16x8 Ah[8][4];
        #pragma unroll
        for (int mt = 0; mt < 8; ++mt)
            #pragma unroll
            for (int kt = 0; kt < 4; ++kt)
                Ah[mt][kt] = afrag_s(W_hh1 + (mt*16 + n)*HH + kt*32 + q*8, SCALE);
        f16x8 bh2[4];
        #pragma unroll
        for (int kt = 0; kt < 4; ++kt) bh2[kt] = (f16x8)(_Float16)0;

        unsigned prod = 0, cons = 0;
        const int l7 = lane & 7;
        for (int t = 0; t < maxlen; ++t){
            if (prod <= (unsigned)t){
                do { prod = ld_flag(&flg[2]); } while (prod <= (unsigned)t);
            }
            if (t >= 4 && cons < (unsigned)(t-3)){
                do { cons = ld_flag(&flg[5]); } while (cons < (unsigned)(t-3));
            }
            f32x4 z[8];
            const f32x4* us = uslot[t & 3];
            #pragma unroll
            for (int mt = 0; mt < 8; ++mt) z[mt] = us[lane*8 + (mt ^ l7)];
            #pragma unroll
            for (int kt = 0; kt < 4; ++kt)
                #pragma unroll
                for (int mt = 0; mt < 8; ++mt)
                    z[mt] = MFMA16(Ah[mt][kt], bh2[kt], z[mt]);

            unsigned P[8][2];
            tanh_pack(z, P);
            unsigned* slot = h2slot[t & 3];
            write_pack(slot, n, q, swz, P);
            read_frags(slot, n, q, swz, bh2);
            if (lane == 0){ st_flag(&flg[3], (unsigned)(t+1)); st_flag(&flg[4], (unsigned)(t+1)); }
        }
    } else {
        // ---------------- wave C: fc ----------------
        f16x8 Af[2][4]; f32x4 bfv[2];
        #pragma unroll
        for (int mt = 0; mt < 2; ++mt){
            #pragma unroll
            for (int kt = 0; kt < 4; ++kt)
                Af[mt][kt] = afrag_s(W_fc + (mt*16 + n)*HH + kt*32 + q*8, 1.0f);
            bfv[mt] = load4(b_fc + mt*16 + q*4);
        }
        float* ob = out + (size_t)(rbase + n)*TT*OO + q*4;
        unsigned prod = 0;
        for (int t = 0; t < maxlen; ++t){
            if (prod <= (unsigned)t){
                do { prod = ld_flag(&flg[4]); } while (prod <= (unsigned)t);
            }
            f16x8 bh2[4];
            read_frags(h2slot[t & 3], n, q, swz, bh2);
            f32x4 zf0 = bfv[0], zf1 = bfv[1];
            #pragma unroll
            for (int kt = 0; kt < 4; ++kt){
                zf0 = MFMA16(Af[0][kt], bh2[kt], zf0);
                zf1 = MFMA16(Af[1][kt], bh2[kt], zf1);
            }
            if (lane == 0) st_flag(&flg[5], (unsigned)(t+1));
            if (t < lenn){
                float4 s0; s0.x=zf0[0]; s0.y=zf0[1]; s0.z=zf0[2]; s0.w=zf0[3];
                float4 s1; s1.x=zf1[0]; s1.y=zf1[1]; s1.z=zf1[2]; s1.w=zf1[3];
                *(float4*)(ob + (size_t)t*OO)      = s0;
                *(float4*)(ob + (size_t)t*OO + 16) = s1;
            }
        }
    }
}

// ---------------------------------------------------------------------------
extern "C" void kernel_launch(void* const* d_in, const int* in_sizes, int n_in,
                              void* d_out, int out_size, void* d_ws, size_t ws_size,
                              hipStream_t stream)
{
    const float* x       = (const float*)d_in[0];
    const int*   lengths = (const int*)  d_in[1];
    const float* W_ih0   = (const float*)d_in[2];
    const float* W_hh0   = (const float*)d_in[3];
    const float* b_ih0   = (const float*)d_in[4];
    const float* b_hh0   = (const float*)d_in[5];
    const float* W_ih1   = (const float*)d_in[6];
    const float* W_hh1   = (const float*)d_in[7];
    const float* b_ih1   = (const float*)d_in[8];
    const float* b_hh1   = (const float*)d_in[9];
    const float* W_fc    = (const float*)d_in[10];
    const float* b_fc    = (const float*)d_in[11];

    _Float16* xp = (_Float16*)d_ws;   // [B*T][128] fp16 = 64 MiB (pre-scaled)

    proj_kernel<<<BB*TT/64, 256, 0, stream>>>(x, W_ih0, b_ih0, b_hh0, xp);
    fill_kernel<<<2048, 256, 0, stream>>>(lengths, b_fc, (float*)d_out);
    scan_pipe<<<BB/NB, 256, 0, stream>>>(xp, lengths, W_hh0,
                                         W_ih1, W_hh1, b_ih1, b_hh1,
                                         W_fc, b_fc, (float*)d_out);
}

// Round 8
// 1629.190 us; speedup vs baseline: 2.5280x; 2.5280x over previous
//
#include <hip/hip_runtime.h>

#define BB 128
#define TT 2048
#define DD 64
#define HH 128
#define OO 32
#define NB 16
#define SCALE 2.885390081777927f   // 2/ln2 folded into weights: tanh = 1-2*rcp(1+exp2(z))

typedef _Float16 f16x8 __attribute__((ext_vector_type(8)));
typedef __fp16   pk16x2 __attribute__((ext_vector_type(2)));
typedef float    f32x4 __attribute__((ext_vector_type(4)));

#define MFMA16(a,b,c) __builtin_amdgcn_mfma_f32_16x16x32_f16((a),(b),(c),0,0,0)

__device__ __forceinline__ f32x4 load4(const float* p){ return *(const f32x4*)p; }

// A-fragment for 16x16x32 (A[m=lane&15][k=(lane>>4)*8+j]), scaled on load.
__device__ __forceinline__ f16x8 afrag_s(const float* p, float s){
    float4 a = *(const float4*)p, b = *(const float4*)(p+4);
    f16x8 r;
    r[0]=(_Float16)(a.x*s); r[1]=(_Float16)(a.y*s); r[2]=(_Float16)(a.z*s); r[3]=(_Float16)(a.w*s);
    r[4]=(_Float16)(b.x*s); r[5]=(_Float16)(b.y*s); r[6]=(_Float16)(b.z*s); r[7]=(_Float16)(b.w*s);
    return r;
}

// tanh with z = SCALE*u pre-folded: e = 2^z = e^{2u}; tanh = 1 - 2/(1+e).
__device__ __forceinline__ float tanh_pre(float z){
#if __has_builtin(__builtin_amdgcn_exp2f)
    float e = __builtin_amdgcn_exp2f(z);
#else
    float e = exp2f(z);
#endif
    return __builtin_fmaf(-2.f, __builtin_amdgcn_rcpf(1.f + e), 1.f);
}

__device__ __forceinline__ unsigned pk2(float a, float b){
    union { pk16x2 h; unsigned u; } c;
    c.h = __builtin_amdgcn_cvt_pkrtz(a, b);
    return c.u;
}

// ---------------------------------------------------------------------------
// proj: xp0[bt][i] = SCALE * (W_ih0[i,:].x[bt,:] + b_ih0[i] + b_hh0[i]), fp16.
// ---------------------------------------------------------------------------
#define XSTR 72
extern "C" __global__ void __launch_bounds__(256)
proj_kernel(const float* __restrict__ x, const float* __restrict__ W_ih0,
            const float* __restrict__ b_ih0, const float* __restrict__ b_hh0,
            _Float16* __restrict__ xp0)
{
    const int tid = threadIdx.x;
    const int w = tid >> 6, lane = tid & 63;
    const int n = lane & 15, q = lane >> 4;
    const size_t row0 = (size_t)blockIdx.x * 64;

    __shared__ __align__(16) _Float16 XT[64][XSTR];

    #pragma unroll
    for (int it = 0; it < 4; ++it){
        float4 v = *(const float4*)(x + row0*DD + it*1024 + tid*4);
        int rr = it*16 + (tid >> 4), d0 = (tid & 15)*4;
        union { uint2 u; _Float16 h[4]; } c;
        c.h[0]=(_Float16)v.x; c.h[1]=(_Float16)v.y; c.h[2]=(_Float16)v.z; c.h[3]=(_Float16)v.w;
        *(uint2*)&XT[rr][d0] = c.u;
    }

    f16x8 A[8][2]; f32x4 bv[8];
    #pragma unroll
    for (int mt = 0; mt < 8; ++mt){
        #pragma unroll
        for (int kt = 0; kt < 2; ++kt)
            A[mt][kt] = afrag_s(W_ih0 + (mt*16 + n)*DD + kt*32 + q*8, SCALE);
        bv[mt] = (load4(b_ih0 + mt*16 + q*4) + load4(b_hh0 + mt*16 + q*4)) * SCALE;
    }
    __syncthreads();

    const _Float16* xr = &XT[w*16 + n][0];
    f16x8 B0 = *(const f16x8*)(xr + q*8);
    f16x8 B1 = *(const f16x8*)(xr + 32 + q*8);

    _Float16* orow = xp0 + (row0 + w*16 + n)*HH + q*4;
    #pragma unroll
    for (int mt = 0; mt < 8; ++mt){
        f32x4 acc = bv[mt];
        acc = MFMA16(A[mt][0], B0, acc);
        acc = MFMA16(A[mt][1], B1, acc);
        union { uint2 u; _Float16 h[4]; } s;
        #pragma unroll
        for (int r = 0; r < 4; ++r) s.h[r] = (_Float16)acc[r];
        *(uint2*)(orow + mt*16) = s.u;
    }
}

// ---------------------------------------------------------------------------
// fill: out[b][t][:] = b_fc for t >= lengths[b].
// ---------------------------------------------------------------------------
extern "C" __global__ void __launch_bounds__(256)
fill_kernel(const int* __restrict__ lengths, const float* __restrict__ b_fc,
            float* __restrict__ out)
{
    size_t idx = (size_t)blockIdx.x*256 + threadIdx.x;
    #pragma unroll
    for (int k = 0; k < 4; ++k, idx += (size_t)2048*256){
        int o4 = (int)(idx & 7);
        int t  = (int)((idx >> 3) & 2047);
        int b  = (int)(idx >> 14);
        if (t >= lengths[b])
            ((float4*)out)[idx] = *(const float4*)(b_fc + o4*4);
    }
}

// ---------------------------------------------------------------------------
// scan: round-3 structure (8 blocks x 4 waves, m-split, one raw barrier/step)
// + 2x unroll with NAMED xp slots (no register moves of in-flight loads ->
// no per-step vmcnt exposure), clamped unconditional reload (no branch),
// SCALE pre-folded, pkrtz packing.
// ---------------------------------------------------------------------------
#define LSTR 136   // halves; 272B rows, 16B-aligned fragments

#define STEP(T_, P_, XA_, XB_) do {                                           \
    const int t_ = (T_);                                                      \
    f16x8 bh1[4], bh2[4];                                                     \
    _Pragma("unroll")                                                         \
    for (int kt = 0; kt < 4; ++kt){                                           \
        bh1[kt] = *(const f16x8*)&H1T[P_][n][kt*32 + q*8];                    \
        bh2[kt] = *(const f16x8*)&H2T[P_][n][kt*32 + q*8];                    \
    }                                                                         \
    f32x4 z0[2];                                                              \
    const bool doZ0 = (t_ < maxlen);                                          \
    if (doZ0){                                                                \
        union { uint2 u; _Float16 h[4]; } cA, cB; cA.u = XA_; cB.u = XB_;     \
        _Pragma("unroll")                                                     \
        for (int r = 0; r < 4; ++r){ z0[0][r] = (float)cA.h[r];               \
                                     z0[1][r] = (float)cB.h[r]; }             \
        _Pragma("unroll")                                                     \
        for (int kt = 0; kt < 4; ++kt){                                       \
            z0[0] = MFMA16(A0[0][kt], bh1[kt], z0[0]);                        \
            z0[1] = MFMA16(A0[1][kt], bh1[kt], z0[1]);                        \
        }                                                                     \
    }                                                                         \
    {   /* unconditional clamped reload into the SAME named slot */           \
        const int tl = (t_ + 2 < TT) ? (t_ + 2) : (TT - 1);                   \
        XA_ = *(const uint2*)(xpbase + (size_t)tl*HH);                        \
        XB_ = *(const uint2*)(xpbase + (size_t)tl*HH + 16);                   \
    }                                                                         \
    f32x4 z1[2];                                                              \
    const bool doZ1 = (t_ >= 1) && (t_ <= maxlen);                            \
    if (doZ1){                                                                \
        f32x4 y0, y1;                                                         \
        z1[0] = b1v[0]; z1[1] = b1v[1];                                       \
        y0[0]=0.f;y0[1]=0.f;y0[2]=0.f;y0[3]=0.f; y1=y0;                       \
        _Pragma("unroll")                                                     \
        for (int kt = 0; kt < 4; ++kt){                                       \
            z1[0] = MFMA16(Ai[0][kt], bh1[kt], z1[0]);                        \
            z1[1] = MFMA16(Ai[1][kt], bh1[kt], z1[1]);                        \
            y0    = MFMA16(Ah[0][kt], bh2[kt], y0);                           \
            y1    = MFMA16(Ah[1][kt], bh2[kt], y1);                           \
        }                                                                     \
        z1[0] += y0; z1[1] += y1;                                             \
    }                                                                         \
    if (w >= 2 && t_ >= 2){                                                   \
        f32x4 zf = bfv;                                                       \
        _Pragma("unroll")                                                     \
        for (int kt = 0; kt < 4; ++kt) zf = MFMA16(Af[kt], bh2[kt], zf);      \
        if (t_ - 2 < lenn){                                                   \
            float4 sv; sv.x=zf[0]; sv.y=zf[1]; sv.z=zf[2]; sv.w=zf[3];        \
            *(float4*)(obase + (size_t)(t_-2)*OO) = sv;                       \
        }                                                                     \
    }                                                                         \
    if (doZ0){                                                                \
        _Pragma("unroll")                                                     \
        for (int m = 0; m < 2; ++m){                                          \
            uint2 v;                                                          \
            v.x = pk2(tanh_pre(z0[m][0]), tanh_pre(z0[m][1]));                \
            v.y = pk2(tanh_pre(z0[m][2]), tanh_pre(z0[m][3]));                \
            *(uint2*)&H1T[(P_)^1][n][(2*w+m)*16 + q*4] = v;                   \
        }                                                                     \
    }                                                                         \
    if (doZ1){                                                                \
        _Pragma("unroll")                                                     \
        for (int m = 0; m < 2; ++m){                                          \
            uint2 v;                                                          \
            v.x = pk2(tanh_pre(z1[m][0]), tanh_pre(z1[m][1]));                \
            v.y = pk2(tanh_pre(z1[m][2]), tanh_pre(z1[m][3]));                \
            *(uint2*)&H2T[(P_)^1][n][(2*w+m)*16 + q*4] = v;                   \
        }                                                                     \
    }                                                                         \
    asm volatile("s_waitcnt lgkmcnt(0)\n\ts_barrier" ::: "memory");           \
} while (0)

extern "C" __global__ void __launch_bounds__(256, 1)
scan_kernel(const _Float16* __restrict__ xp0, const int* __restrict__ lengths,
            const float* __restrict__ W_hh0,
            const float* __restrict__ W_ih1, const float* __restrict__ W_hh1,
            const float* __restrict__ b_ih1, const float* __restrict__ b_hh1,
            const float* __restrict__ W_fc,  const float* __restrict__ b_fc,
            float* __restrict__ out)
{
    const int tid  = threadIdx.x;
    const int w    = tid >> 6, lane = tid & 63;
    const int n    = lane & 15, q = lane >> 4;
    const int rbase= blockIdx.x * NB;

    __shared__ __align__(16) _Float16 H1T[2][NB][LSTR];
    __shared__ __align__(16) _Float16 H2T[2][NB][LSTR];

    for (int idx = tid; idx < 2*NB*LSTR/2; idx += 256){
        ((unsigned*)H1T)[idx] = 0u;
        ((unsigned*)H2T)[idx] = 0u;
    }

    // ---- stationary weights as A-fragments (SCALE pre-folded) ----
    f16x8 A0[2][4], Ai[2][4], Ah[2][4];
    #pragma unroll
    for (int m = 0; m < 2; ++m){
        const int row = (2*w + m)*16 + n;
        #pragma unroll
        for (int kt = 0; kt < 4; ++kt){
            A0[m][kt] = afrag_s(W_hh0 + row*HH + kt*32 + q*8, SCALE);
            Ai[m][kt] = afrag_s(W_ih1 + row*HH + kt*32 + q*8, SCALE);
            Ah[m][kt] = afrag_s(W_hh1 + row*HH + kt*32 + q*8, SCALE);
        }
    }
    const int f = w & 1;
    f16x8 Af[4];
    #pragma unroll
    for (int kt = 0; kt < 4; ++kt)
        Af[kt] = afrag_s(W_fc + (f*16 + n)*HH + kt*32 + q*8, 1.0f);

    f32x4 b1v[2];
    #pragma unroll
    for (int m = 0; m < 2; ++m)
        b1v[m] = (load4(b_ih1 + (2*w+m)*16 + q*4) + load4(b_hh1 + (2*w+m)*16 + q*4)) * SCALE;
    const f32x4 bfv = load4(b_fc + f*16 + q*4);

    const int lenn = lengths[rbase + n];
    int mx = lenn;
    #pragma unroll
    for (int s = 1; s < 16; s <<= 1){ int o = __shfl_xor(mx, s, 64); mx = max(mx, o); }
    const int maxlen = __builtin_amdgcn_readfirstlane(mx);

    const _Float16* xpbase = xp0 + ((size_t)(rbase+n)*TT)*HH + (2*w)*16 + q*4;
    float* obase = out + ((size_t)(rbase+n)*TT)*OO + f*16 + q*4;

    // ---- xp prefetch: 2 NAMED slots, distance 2, no rotation ----
    uint2 xeA = *(const uint2*)(xpbase);
    uint2 xeB = *(const uint2*)(xpbase + 16);
    uint2 xoA = *(const uint2*)(xpbase + HH);
    uint2 xoB = *(const uint2*)(xpbase + HH + 16);

    __syncthreads();

    for (int t0 = 0; t0 <= maxlen + 1; t0 += 2){
        STEP(t0,     0, xeA, xeB);
        STEP(t0 + 1, 1, xoA, xoB);
    }
}

// ---------------------------------------------------------------------------
extern "C" void kernel_launch(void* const* d_in, const int* in_sizes, int n_in,
                              void* d_out, int out_size, void* d_ws, size_t ws_size,
                              hipStream_t stream)
{
    const float* x       = (const float*)d_in[0];
    const int*   lengths = (const int*)  d_in[1];
    const float* W_ih0   = (const float*)d_in[2];
    const float* W_hh0   = (const float*)d_in[3];
    const float* b_ih0   = (const float*)d_in[4];
    const float* b_hh0   = (const float*)d_in[5];
    const float* W_ih1   = (const float*)d_in[6];
    const float* W_hh1   = (const float*)d_in[7];
    const float* b_ih1   = (const float*)d_in[8];
    const float* b_hh1   = (const float*)d_in[9];
    const float* W_fc    = (const float*)d_in[10];
    const float* b_fc    = (const float*)d_in[11];

    _Float16* xp = (_Float16*)d_ws;   // [B*T][128] fp16 = 64 MiB (pre-scaled)

    proj_kernel<<<BB*TT/64, 256, 0, stream>>>(x, W_ih0, b_ih0, b_hh0, xp);
    fill_kernel<<<2048, 256, 0, stream>>>(lengths, b_fc, (float*)d_out);
    scan_kernel<<<BB/NB, 256, 0, stream>>>(xp, lengths, W_hh0,
                                           W_ih1, W_hh1, b_ih1, b_hh1,
                                           W_fc, b_fc, (float*)d_out);
}